// Round 1
// 596.090 us; speedup vs baseline: 1.0275x; 1.0275x over previous
//
#include <hip/hip_runtime.h>

#define N_NODES 200000
#define N_EDGES 1200000
#define F_IN    64
#define F_H     128
#define BN_EPS  1e-5f

typedef short bf16x8 __attribute__((ext_vector_type(8)));   // 8 bf16 in 4 VGPRs
typedef float f32x4  __attribute__((ext_vector_type(4)));
typedef unsigned short us4 __attribute__((ext_vector_type(4)));

__device__ __forceinline__ unsigned short f2bf(float f) {
    union { float f; unsigned u; } v; v.f = f;
    unsigned r = (v.u + 0x7FFFu + ((v.u >> 16) & 1u)) >> 16;  // RNE
    return (unsigned short)r;
}
__device__ __forceinline__ float bf2f(unsigned short b) {
    union { unsigned u; float f; } v; v.u = ((unsigned)b) << 16;
    return v.f;
}

// ---------------------------------------------------------------------------
// Weight pack into bf16 MFMA B-fragment order for mfma_f32_16x16x32_bf16.
// ---------------------------------------------------------------------------
__global__ void pack_weights_kernel(const float* __restrict__ W,
                                    const float* __restrict__ kscale,
                                    short* __restrict__ P, int KT)
{
    int t = blockIdx.x * 256 + threadIdx.x;            // over 8*KT*64
    if (t >= 8 * KT * 64) return;
    int lane = t & 63;
    int kt   = (t >> 6) % KT;
    int nt   = t / (64 * KT);
    int k0   = kt * 32 + (lane >> 4) * 8;
    int n    = nt * 16 + (lane & 15);
#pragma unroll
    for (int j = 0; j < 8; ++j) {
        float w = W[(size_t)(k0 + j) * 128 + n];
        if (kscale) w *= kscale[k0 + j];
        P[(size_t)t * 8 + j] = (short)f2bf(w);
    }
}

// ---------------------------------------------------------------------------
// CSR build: histogram -> 2-level exclusive scan -> cursor fill
// ---------------------------------------------------------------------------
__global__ __launch_bounds__(256) void hist_kernel(const int* __restrict__ ei,
                                                   int* __restrict__ deg, int E)
{
    int e = blockIdx.x * 256 + threadIdx.x;
    if (e < E) atomicAdd(&deg[ei[E + e]], 1);
}

__global__ __launch_bounds__(256) void scan1_kernel(const int* __restrict__ deg,
        int* __restrict__ part, int* __restrict__ bsum, int n)
{
    __shared__ int s[256];
    int t = threadIdx.x;
    int base = blockIdx.x * 1024 + t * 4;
    int v[4];
#pragma unroll
    for (int j = 0; j < 4; ++j) v[j] = (base + j < n) ? deg[base + j] : 0;
    int tsum = v[0] + v[1] + v[2] + v[3];
    s[t] = tsum;
    __syncthreads();
    for (int off = 1; off < 256; off <<= 1) {
        int xv = (t >= off) ? s[t - off] : 0;
        __syncthreads();
        s[t] += xv;
        __syncthreads();
    }
    int excl = s[t] - tsum;
#pragma unroll
    for (int j = 0; j < 4; ++j) {
        if (base + j < n) part[base + j] = excl;
        excl += v[j];
    }
    if (t == 255) bsum[blockIdx.x] = s[255];
}

__global__ void scan2_kernel(int* __restrict__ bsum, int nb)
{
    __shared__ int s[256];
    int t = threadIdx.x;
    int v = (t < nb) ? bsum[t] : 0;
    s[t] = v;
    __syncthreads();
    for (int off = 1; off < 256; off <<= 1) {
        int xv = (t >= off) ? s[t - off] : 0;
        __syncthreads();
        s[t] += xv;
        __syncthreads();
    }
    if (t < nb) bsum[t] = s[t] - v;   // exclusive
}

__global__ __launch_bounds__(256) void scan3_kernel(
    const int* __restrict__ part, const int* __restrict__ bsum,
    const int* __restrict__ deg, int* __restrict__ rowptr,
    int* __restrict__ cursor, float* __restrict__ degf, int n, int E)
{
    int i = blockIdx.x * 256 + threadIdx.x;
    if (i == 0) rowptr[n] = E;
    if (i >= n) return;
    int r = part[i] + bsum[i >> 10];
    rowptr[i] = r;
    cursor[i] = r;
    degf[i]   = (float)deg[i];
}

__global__ __launch_bounds__(256) void fill_kernel(const int* __restrict__ ei,
        int* __restrict__ cursor, int* __restrict__ ssrc, int E)
{
    int e = blockIdx.x * 256 + threadIdx.x;
    if (e >= E) return;
    int d = ei[E + e];
    int pos = atomicAdd(&cursor[d], 1);
    ssrc[pos] = ei[e];
}

// ---------------------------------------------------------------------------
// Gather layer 1: aggb[row,0:64] = bf16( sum_src x[src,:] ).
// 4 rows/wave; neighbors batched x8 (8 feature loads + 8 index prefetches in
// flight per iteration; masked slots clamp to `row` and multiply by 0).
// ---------------------------------------------------------------------------
__global__ __launch_bounds__(256) void gather1_kernel(
    const float* __restrict__ x, const int* __restrict__ rowptr,
    const int* __restrict__ ssrc, unsigned short* __restrict__ aggb)
{
    const int tid  = threadIdx.x;
    const int wv   = tid >> 6;
    const int lane = tid & 63;
    const int sub  = lane >> 4;
    const int li   = lane & 15;
    const int row  = blockIdx.x * 16 + wv * 4 + sub;

    const int b = rowptr[row], e = rowptr[row + 1];
    float4 acc = {0.f, 0.f, 0.f, 0.f};
    int s[8];
#pragma unroll
    for (int q = 0; q < 8; ++q) s[q] = (b + q < e) ? ssrc[b + q] : row;
    for (int j = b; j < e; j += 8) {
        int nn[8];
        const int jn = j + 8;
#pragma unroll
        for (int q = 0; q < 8; ++q) nn[q] = (jn + q < e) ? ssrc[jn + q] : row;
        float4 v[8];
#pragma unroll
        for (int q = 0; q < 8; ++q)
            v[q] = ((const float4*)(x + (size_t)s[q] * F_IN))[li];
#pragma unroll
        for (int q = 0; q < 8; ++q) {
            float w = (j + q < e) ? 1.f : 0.f;
            acc.x = fmaf(v[q].x, w, acc.x);
            acc.y = fmaf(v[q].y, w, acc.y);
            acc.z = fmaf(v[q].z, w, acc.z);
            acc.w = fmaf(v[q].w, w, acc.w);
        }
#pragma unroll
        for (int q = 0; q < 8; ++q) s[q] = nn[q];
    }
    us4 o;
    o.x = f2bf(acc.x); o.y = f2bf(acc.y); o.z = f2bf(acc.z); o.w = f2bf(acc.w);
    *(us4*)(aggb + (size_t)row * F_IN + li * 4) = o;
}

// ---------------------------------------------------------------------------
// Gather layer 2: aggb[row,0:128] = bf16( sum_src t1[src,:] ), batch x8.
// ---------------------------------------------------------------------------
__global__ __launch_bounds__(256) void gather2_kernel(
    const unsigned short* __restrict__ t1, const int* __restrict__ rowptr,
    const int* __restrict__ ssrc, unsigned short* __restrict__ aggb)
{
    const int tid  = threadIdx.x;
    const int wv   = tid >> 6;
    const int lane = tid & 63;
    const int sub  = lane >> 4;
    const int li   = lane & 15;
    const int row  = blockIdx.x * 16 + wv * 4 + sub;

    const int b = rowptr[row], e = rowptr[row + 1];
    float acc[8] = {};
    int s[8];
#pragma unroll
    for (int q = 0; q < 8; ++q) s[q] = (b + q < e) ? ssrc[b + q] : row;
    for (int j = b; j < e; j += 8) {
        int nn[8];
        const int jn = j + 8;
#pragma unroll
        for (int q = 0; q < 8; ++q) nn[q] = (jn + q < e) ? ssrc[jn + q] : row;
        bf16x8 v[8];
#pragma unroll
        for (int q = 0; q < 8; ++q)
            v[q] = *(const bf16x8*)(t1 + (size_t)s[q] * F_H + li * 8);
#pragma unroll
        for (int q = 0; q < 8; ++q) {
            float w = (j + q < e) ? 1.f : 0.f;
#pragma unroll
            for (int k = 0; k < 8; ++k)
                acc[k] = fmaf(bf2f((unsigned short)v[q][k]), w, acc[k]);
        }
#pragma unroll
        for (int q = 0; q < 8; ++q) s[q] = nn[q];
    }
    bf16x8 o;
#pragma unroll
    for (int k = 0; k < 8; ++k) o[k] = (short)f2bf(acc[k]);
    *(bf16x8*)(aggb + (size_t)row * F_H + li * 8) = o;
}

// ---------------------------------------------------------------------------
// MFMA GEMM: 32 rows/wave (2 subtiles), 128 rows/block, flat grid 1563.
// ALL A/X row-slices for the wave are loaded up front (K=128: 16 x 1KB loads
// = 16 KB/wave in flight; Little's law).
//
// R8 change: weights are staged ONCE per block into LDS (64 KB for K=128,
// 32 KB for K=64) and the K-loop reads fragments via lane-consecutive
// ds_read_b128 (conflict-free). Rationale: VGPR_Count=64 with 64 VGPRs of
// A/X row data left the compiler ZERO headroom to pipeline the 64 global
// weight loads per wave, and the 64 KB weight set thrashed the 32 KB L1 —
// each wave paid ~64 serialized L2-latency hops (MfmaUtil 4.7%, HBM 1.5
// TB/s, 90% stall). LDS reads need no VGPR pipelining (compiler emits
// fine-grained lgkmcnt) and are read once per block from L2 instead of
// once per wave.
// Stats buffers are OVERLAID on the weight LDS after the K-loop (barrier-
// separated) to stay within the 64 KB/block LDS limit.
// ---------------------------------------------------------------------------
template<int K, bool L2>
__global__ __launch_bounds__(256, 2) void gemm_mfma_kernel(
    const unsigned short* __restrict__ Ab,
    const float* __restrict__ Xf,
    const unsigned short* __restrict__ Xb,
    const bf16x8* __restrict__ Wlp, const bf16x8* __restrict__ Wrp,
    const float* __restrict__ bias,
    const float* __restrict__ c2, const float* __restrict__ degf,
    float* __restrict__ outF, unsigned short* __restrict__ outB,
    float* __restrict__ gsum, float* __restrict__ gsq)
{
    constexpr int KT = K / 32;
    constexpr int WHALF = 8 * KT * 64 * 8;        // shorts per weight array
    __shared__ short sW[2 * WHALF];               // Wl | Wr (stats overlaid later)

    const int tid  = threadIdx.x;
    const int lane = tid & 63;
    const int wv   = tid >> 6;
    const int m    = lane & 15;
    const int quad = lane >> 4;
    const int rowbase = blockIdx.x * 128 + wv * 32;

    int rc[2];
#pragma unroll
    for (int st = 0; st < 2; ++st) {
        int r = rowbase + st * 16 + m;
        rc[st] = r < N_NODES ? r : N_NODES - 1;
    }

    // ---- upfront load of the wave's full A and X row-slices (HBM/L3) ----
    bf16x8 aReg[2][KT], xReg[2][KT];
#pragma unroll
    for (int st = 0; st < 2; ++st) {
        const unsigned short* ap = Ab + (size_t)rc[st] * K + quad * 8;
#pragma unroll
        for (int kt = 0; kt < KT; ++kt)
            aReg[st][kt] = *(const bf16x8*)(ap + kt * 32);
    }
    if constexpr (L2) {
#pragma unroll
        for (int st = 0; st < 2; ++st) {
            const unsigned short* xp = Xb + (size_t)rc[st] * K + quad * 8;
#pragma unroll
            for (int kt = 0; kt < KT; ++kt)
                xReg[st][kt] = *(const bf16x8*)(xp + kt * 32);
        }
    } else {
        float4 xr[2][KT][2];
#pragma unroll
        for (int st = 0; st < 2; ++st) {
            const float* xp = Xf + (size_t)rc[st] * K + quad * 8;
#pragma unroll
            for (int kt = 0; kt < KT; ++kt) {
                xr[st][kt][0] = *(const float4*)(xp + kt * 32);
                xr[st][kt][1] = *(const float4*)(xp + kt * 32 + 4);
            }
        }
#pragma unroll
        for (int st = 0; st < 2; ++st)
#pragma unroll
            for (int kt = 0; kt < KT; ++kt) {
                xReg[st][kt][0] = (short)f2bf(xr[st][kt][0].x);
                xReg[st][kt][1] = (short)f2bf(xr[st][kt][0].y);
                xReg[st][kt][2] = (short)f2bf(xr[st][kt][0].z);
                xReg[st][kt][3] = (short)f2bf(xr[st][kt][0].w);
                xReg[st][kt][4] = (short)f2bf(xr[st][kt][1].x);
                xReg[st][kt][5] = (short)f2bf(xr[st][kt][1].y);
                xReg[st][kt][6] = (short)f2bf(xr[st][kt][1].z);
                xReg[st][kt][7] = (short)f2bf(xr[st][kt][1].w);
            }
    }

    // ---- stage packed weights into LDS (cooperative, once per block) ----
    {
        const short* wl = (const short*)Wlp;
        const short* wr = (const short*)Wrp;
#pragma unroll 4
        for (int i = 0; i < WHALF / (256 * 8); ++i) {
            int idx = (i * 256 + tid) * 8;
            *(bf16x8*)(sW + idx)         = *(const bf16x8*)(wl + idx);
            *(bf16x8*)(sW + WHALF + idx) = *(const bf16x8*)(wr + idx);
        }
    }

    // per-nt epilogue constants (col = nt*16 + m)
    float bcol[8], ccol[8];
#pragma unroll
    for (int nt = 0; nt < 8; ++nt) {
        bcol[nt] = bias[nt * 16 + m];
        if constexpr (L2) ccol[nt] = c2[nt * 16 + m];
    }

    f32x4 acc[2][8] = {};

    __syncthreads();   // weights staged (also drains this wave's A/X loads)

    // ---- K loop: LDS weight reads (ds_read_b128, conflict-free) + MFMA ----
    const short* wlL = sW + lane * 8;          // lane-consecutive 16B frags
    const short* wrL = sW + WHALF + lane * 8;
#pragma unroll
    for (int kt = 0; kt < KT; ++kt) {
#pragma unroll
        for (int nt = 0; nt < 8; ++nt) {
            bf16x8 wl = *(const bf16x8*)(wlL + (nt * KT + kt) * 512);
#pragma unroll
            for (int st = 0; st < 2; ++st)
                acc[st][nt] = __builtin_amdgcn_mfma_f32_16x16x32_bf16(
                    aReg[st][kt], wl, acc[st][nt], 0, 0, 0);
            bf16x8 wr = *(const bf16x8*)(wrL + (nt * KT + kt) * 512);
#pragma unroll
            for (int st = 0; st < 2; ++st)
                acc[st][nt] = __builtin_amdgcn_mfma_f32_16x16x32_bf16(
                    xReg[st][kt], wr, acc[st][nt], 0, 0, 0);
        }
    }

    // ---- epilogue: C/D layout col = lane&15, row = quad*4 + reg ----
    float stS[8] = {}, stQ[8] = {};
#pragma unroll
    for (int st = 0; st < 2; ++st) {
        const int orow = rowbase + st * 16 + quad * 4;
        float dg[4];
        if constexpr (L2) {
#pragma unroll
            for (int r = 0; r < 4; ++r) {
                int rr = orow + r;
                dg[r] = (rr < N_NODES) ? degf[rr] : 0.f;
            }
        }
#pragma unroll
        for (int nt = 0; nt < 8; ++nt) {
            int col = nt * 16 + m;
#pragma unroll
            for (int r = 0; r < 4; ++r) {
                int rr = orow + r;
                if (rr < N_NODES) {
                    float base = L2 ? fmaf(dg[r], ccol[nt], bcol[nt]) : bcol[nt];
                    float v = fmaxf(acc[st][nt][r] + base, 0.f);
                    if constexpr (L2) outF[(size_t)rr * 128 + col] = v;
                    else              outB[(size_t)rr * 128 + col] = f2bf(v);
                    stS[nt] += v;
                    stQ[nt] = fmaf(v, v, stQ[nt]);
                }
            }
        }
    }

    // ---- stats reduce: overlay sS/sQ on the (now dead) weight LDS ----
    float* sS = (float*)sW;
    float* sQ = ((float*)sW) + 128;
    __syncthreads();                      // all weight reads complete
    if (tid < 128) { sS[tid] = 0.f; sQ[tid] = 0.f; }
    __syncthreads();
#pragma unroll
    for (int nt = 0; nt < 8; ++nt) {
        atomicAdd(&sS[nt * 16 + m], stS[nt]);
        atomicAdd(&sQ[nt * 16 + m], stQ[nt]);
    }
    __syncthreads();
    const int rep = (blockIdx.x & 3) * 128;
    if (tid < 128) {
        atomicAdd(&gsum[rep + tid], sS[tid]);
        atomicAdd(&gsq[rep + tid],  sQ[tid]);
    }
}

// ---------------------------------------------------------------------------
// BN finalize: per-feature scale/shift (sums the 4 stats replicas).
// ---------------------------------------------------------------------------
__global__ void bn_finalize_kernel(
    const float* __restrict__ gsum, const float* __restrict__ gsq,
    const float* __restrict__ g, const float* __restrict__ be,
    float* __restrict__ scale, float* __restrict__ shift, float invN)
{
    int c = threadIdx.x;  // 128
    float s = gsum[c] + gsum[128 + c] + gsum[256 + c] + gsum[384 + c];
    float q = gsq[c]  + gsq[128 + c]  + gsq[256 + c]  + gsq[384 + c];
    float mean = s * invN;
    float var  = fmaxf(q * invN - mean * mean, 0.f);
    float sc   = g[c] * rsqrtf(var + BN_EPS);
    scale[c] = sc;
    shift[c] = be[c] - mean * sc;
}

// BN1 fold constants: c2 = shift1@W2l ; crb = shift1@W2r + b2
__global__ void bn_fold_kernel(
    const float* __restrict__ shift1, const float* __restrict__ W2l,
    const float* __restrict__ W2r, const float* __restrict__ b2,
    float* __restrict__ c2, float* __restrict__ crb)
{
    int col = threadIdx.x;  // 128
    float a = 0.f, r = 0.f;
    for (int k = 0; k < 128; ++k) {
        float s = shift1[k];
        a = fmaf(s, W2l[(size_t)k * 128 + col], a);
        r = fmaf(s, W2r[(size_t)k * 128 + col], r);
    }
    c2[col]  = a;
    crb[col] = r + b2[col];
}

// ---------------------------------------------------------------------------
// Final BN apply + ReLU (in place on d_out).
// ---------------------------------------------------------------------------
__global__ __launch_bounds__(256) void bn_apply_relu_kernel(
    float* __restrict__ h, const float* __restrict__ scale,
    const float* __restrict__ shift, int n4)
{
    int i = blockIdx.x * 256 + threadIdx.x;
    if (i >= n4) return;
    int cb = i & 31;
    float4 v  = ((float4*)h)[i];
    float4 sc = ((const float4*)scale)[cb];
    float4 sh = ((const float4*)shift)[cb];
    v.x = fmaxf(fmaf(v.x, sc.x, sh.x), 0.f);
    v.y = fmaxf(fmaf(v.y, sc.y, sh.y), 0.f);
    v.z = fmaxf(fmaf(v.z, sc.z, sh.z), 0.f);
    v.w = fmaxf(fmaf(v.w, sc.w, sh.w), 0.f);
    ((float4*)h)[i] = v;
}

extern "C" void kernel_launch(void* const* d_in, const int* in_sizes, int n_in,
                              void* d_out, int out_size, void* d_ws, size_t ws_size,
                              hipStream_t stream) {
    const float* x   = (const float*)d_in[0];
    const int*   ei  = (const int*)d_in[1];
    const float* W1l = (const float*)d_in[2];
    const float* b1  = (const float*)d_in[3];
    const float* W1r = (const float*)d_in[4];
    const float* g1  = (const float*)d_in[5];
    const float* be1 = (const float*)d_in[6];
    const float* W2l = (const float*)d_in[7];
    const float* b2  = (const float*)d_in[8];
    const float* W2r = (const float*)d_in[9];
    const float* g2  = (const float*)d_in[10];
    const float* be2 = (const float*)d_in[11];
    float* out = (float*)d_out;

    const int N = N_NODES, E = N_EDGES;
    const int NB1 = (N + 1023) / 1024;          // 196 scan blocks
    const int nT  = (N + 127) / 128;            // 1563 gemm blocks

    // Workspace layout (float units):
    float* ws     = (float*)d_ws;
    float* gsum1  = ws;          float* gsq1   = ws + 512;    // 4 replicas x 128
    float* gsum2  = ws + 1024;   float* gsq2   = ws + 1536;
    float* scale1 = ws + 2048;   float* shift1 = ws + 2176;
    float* scale2 = ws + 2304;   float* shift2 = ws + 2432;
    float* c2v    = ws + 2560;   float* crb    = ws + 2688;
    short* W1lp = (short*)(ws + 3072);                        // 4096 f
    short* W1rp = (short*)(ws + 3072 + 4096);                 // 4096 f
    short* W2lp = (short*)(ws + 3072 + 8192);                 // 8192 f
    short* W2rp = (short*)(ws + 3072 + 16384);                // 8192 f
    int*   deg    = (int*)(ws + 27648);                       // N
    int*   part   = deg + N;                                  // N
    int*   bsum   = part + N;                                 // 1024
    int*   rowptr = bsum + 1024;                              // N+1
    int*   cursor = rowptr + (N + 1024);                      // N (padded)
    float* degf   = (float*)(cursor + N);                     // N
    int*   ssrc   = (int*)(degf + N);                         // E
    unsigned short* t1   = (unsigned short*)(ssrc + E);       // N*128 bf16
    unsigned short* aggb = t1 + (size_t)N * F_H;              // N*128 bf16

    // ---- Graph build + layer-1 weight pack ----
    hipMemsetAsync(ws, 0, 2048 * sizeof(float), stream);      // stats replicas
    hipMemsetAsync(deg, 0, (size_t)N * sizeof(int), stream);
    pack_weights_kernel<<<4, 256, 0, stream>>>(W1l, nullptr, W1lp, 2);
    pack_weights_kernel<<<4, 256, 0, stream>>>(W1r, nullptr, W1rp, 2);
    hist_kernel<<<(E + 255) / 256, 256, 0, stream>>>(ei, deg, E);
    scan1_kernel<<<NB1, 256, 0, stream>>>(deg, part, bsum, N);
    scan2_kernel<<<1, 256, 0, stream>>>(bsum, NB1);
    scan3_kernel<<<(N + 255) / 256, 256, 0, stream>>>(part, bsum, deg, rowptr,
                                                      cursor, degf, N, E);
    fill_kernel<<<(E + 255) / 256, 256, 0, stream>>>(ei, cursor, ssrc, E);

    // ---- Layer 1 ----
    gather1_kernel<<<N / 16, 256, 0, stream>>>(x, rowptr, ssrc, aggb);
    gemm_mfma_kernel<F_IN, false><<<nT, 256, 0, stream>>>(
        aggb, x, nullptr, (const bf16x8*)W1lp, (const bf16x8*)W1rp, b1,
        nullptr, nullptr, nullptr, t1, gsum1, gsq1);
    bn_finalize_kernel<<<1, 128, 0, stream>>>(gsum1, gsq1, g1, be1,
                                              scale1, shift1, 1.f / N);

    // ---- Layer 2 (BN1 folded: scale1 into weights, shift1 into c2/crb) ----
    pack_weights_kernel<<<8, 256, 0, stream>>>(W2l, scale1, W2lp, 4);
    pack_weights_kernel<<<8, 256, 0, stream>>>(W2r, scale1, W2rp, 4);
    bn_fold_kernel<<<1, 128, 0, stream>>>(shift1, W2l, W2r, b2, c2v, crb);
    gather2_kernel<<<N / 16, 256, 0, stream>>>(t1, rowptr, ssrc, aggb);
    gemm_mfma_kernel<F_H, true><<<nT, 256, 0, stream>>>(
        aggb, nullptr, t1, (const bf16x8*)W2lp, (const bf16x8*)W2rp, crb,
        c2v, degf, out, nullptr, gsum2, gsq2);
    bn_finalize_kernel<<<1, 128, 0, stream>>>(gsum2, gsq2, g2, be2,
                                              scale2, shift2, 1.f / N);
    bn_apply_relu_kernel<<<(N * F_H / 4 + 255) / 256, 256, 0, stream>>>(
        out, scale2, shift2, N * F_H / 4);
}

// Round 2
// 535.253 us; speedup vs baseline: 1.1443x; 1.1137x over previous
//
#include <hip/hip_runtime.h>

#define N_NODES 200000
#define N_EDGES 1200000
#define F_IN    64
#define F_H     128
#define BN_EPS  1e-5f
#define NBUK    196          // ceil(N/1024) dst-buckets of 1024 nodes
#define BINB    293          // ceil(E/4096) bin blocks

typedef short bf16x8 __attribute__((ext_vector_type(8)));   // 8 bf16 in 4 VGPRs
typedef float f32x4  __attribute__((ext_vector_type(4)));
typedef unsigned short us4 __attribute__((ext_vector_type(4)));

__device__ __forceinline__ unsigned short f2bf(float f) {
    union { float f; unsigned u; } v; v.f = f;
    unsigned r = (v.u + 0x7FFFu + ((v.u >> 16) & 1u)) >> 16;  // RNE
    return (unsigned short)r;
}
__device__ __forceinline__ float bf2f(unsigned short b) {
    union { unsigned u; float f; } v; v.u = ((unsigned)b) << 16;
    return v.f;
}

// ---------------------------------------------------------------------------
// Weight pack into bf16 MFMA B-fragment order for mfma_f32_16x16x32_bf16.
// ---------------------------------------------------------------------------
__global__ void pack_weights_kernel(const float* __restrict__ W,
                                    const float* __restrict__ kscale,
                                    short* __restrict__ P, int KT)
{
    int t = blockIdx.x * 256 + threadIdx.x;            // over 8*KT*64
    if (t >= 8 * KT * 64) return;
    int lane = t & 63;
    int kt   = (t >> 6) % KT;
    int nt   = t / (64 * KT);
    int k0   = kt * 32 + (lane >> 4) * 8;
    int n    = nt * 16 + (lane & 15);
#pragma unroll
    for (int j = 0; j < 8; ++j) {
        float w = W[(size_t)(k0 + j) * 128 + n];
        if (kscale) w *= kscale[k0 + j];
        P[(size_t)t * 8 + j] = (short)f2bf(w);
    }
}

// ---------------------------------------------------------------------------
// CSR build: histogram -> 2-level exclusive scan over deg -> bucketed fill
// ---------------------------------------------------------------------------
__global__ __launch_bounds__(256) void hist_kernel(const int* __restrict__ ei,
                                                   int* __restrict__ deg, int E)
{
    int e = blockIdx.x * 256 + threadIdx.x;
    if (e < E) atomicAdd(&deg[ei[E + e]], 1);
}

__global__ __launch_bounds__(256) void scan1_kernel(const int* __restrict__ deg,
        int* __restrict__ part, int* __restrict__ bsum, int n)
{
    __shared__ int s[256];
    int t = threadIdx.x;
    int base = blockIdx.x * 1024 + t * 4;
    int v[4];
#pragma unroll
    for (int j = 0; j < 4; ++j) v[j] = (base + j < n) ? deg[base + j] : 0;
    int tsum = v[0] + v[1] + v[2] + v[3];
    s[t] = tsum;
    __syncthreads();
    for (int off = 1; off < 256; off <<= 1) {
        int xv = (t >= off) ? s[t - off] : 0;
        __syncthreads();
        s[t] += xv;
        __syncthreads();
    }
    int excl = s[t] - tsum;
#pragma unroll
    for (int j = 0; j < 4; ++j) {
        if (base + j < n) part[base + j] = excl;
        excl += v[j];
    }
    if (t == 255) bsum[blockIdx.x] = s[255];
}

__global__ void scan2_kernel(int* __restrict__ bsum, int nb)
{
    __shared__ int s[256];
    int t = threadIdx.x;
    int v = (t < nb) ? bsum[t] : 0;
    s[t] = v;
    __syncthreads();
    for (int off = 1; off < 256; off <<= 1) {
        int xv = (t >= off) ? s[t - off] : 0;
        __syncthreads();
        s[t] += xv;
        __syncthreads();
    }
    if (t < nb) bsum[t] = s[t] - v;   // exclusive
}

__global__ __launch_bounds__(256) void scan3_kernel(
    const int* __restrict__ part, const int* __restrict__ bsum,
    const int* __restrict__ deg, int* __restrict__ rowptr,
    int* __restrict__ bcursor, float* __restrict__ degf, int n, int E)
{
    int i = blockIdx.x * 256 + threadIdx.x;
    if (i == 0) rowptr[n] = E;
    if (i >= n) return;
    int r = part[i] + bsum[i >> 10];
    rowptr[i] = r;
    if ((i & 1023) == 0) bcursor[i >> 10] = r;   // bucket segment base
    degf[i]   = (float)deg[i];
}

// ---------------------------------------------------------------------------
// bin_kernel: LDS multi-split of edges into 196 contiguous-dst buckets.
// Replaces the random 4B atomic scatter of fill_kernel (WRITE_SIZE was
// 84 MB = 16x amplification). Each block: LDS histogram over buckets ->
// scan -> ONE global atomic per (block,bucket) reserves a contiguous range
// -> bucket-sorted LDS stage -> coalesced runs (~16 edges = 64B) out.
// Edge packed as src<<10 | (dst&1023): src<2^18, dst_local<2^10.
// ---------------------------------------------------------------------------
__global__ __launch_bounds__(256) void bin_kernel(
    const int* __restrict__ ei, int* __restrict__ bcursor,
    unsigned* __restrict__ binned, int E)
{
    __shared__ int lcnt[256];
    __shared__ int lbase[256];
    __shared__ int gbase[256];
    __shared__ int sc[256];
    __shared__ unsigned stage[4096];
    __shared__ unsigned char stgb[4096];
    const int tid  = threadIdx.x;
    const int base = blockIdx.x * 4096;
    lcnt[tid] = 0;
    __syncthreads();

    unsigned val[16]; short lp[16]; unsigned char bk[16];
#pragma unroll
    for (int i = 0; i < 16; ++i) {
        int e = base + i * 256 + tid;
        if (e < E) {
            int s = ei[e], d = ei[E + e];
            int b = d >> 10;
            val[i] = ((unsigned)s << 10) | (unsigned)(d & 1023);
            bk[i]  = (unsigned char)b;
            lp[i]  = (short)atomicAdd(&lcnt[b], 1);
        } else lp[i] = -1;
    }
    __syncthreads();

    // exclusive scan of per-bucket counts + global range reservation
    int c = lcnt[tid];
    sc[tid] = c;
    __syncthreads();
    for (int off = 1; off < 256; off <<= 1) {
        int v = (tid >= off) ? sc[tid - off] : 0;
        __syncthreads();
        sc[tid] += v;
        __syncthreads();
    }
    lbase[tid] = sc[tid] - c;
    if (c) gbase[tid] = atomicAdd(&bcursor[tid], c);
    __syncthreads();
    const int total = sc[255];

    // bucket-sorted stage in LDS
#pragma unroll
    for (int i = 0; i < 16; ++i) {
        if (lp[i] >= 0) {
            int p = lbase[bk[i]] + lp[i];
            stage[p] = val[i];
            stgb[p]  = bk[i];
        }
    }
    __syncthreads();

    // write out: consecutive p within a bucket -> consecutive global addrs
    for (int p = tid; p < total; p += 256) {
        int b = stgb[p];
        binned[gbase[b] + (p - lbase[b])] = stage[p];
    }
}

// ---------------------------------------------------------------------------
// scatter_kernel: one block per bucket. Cursors for the bucket's 1024 dst
// rows live in LDS (no L2 atomic latency); ssrc writes land inside the
// bucket's ~24 KB window -> lines fully written in L2, ~1x amplification.
// ---------------------------------------------------------------------------
__global__ __launch_bounds__(256) void scatter_kernel(
    const unsigned* __restrict__ binned, const int* __restrict__ rowptr,
    int* __restrict__ ssrc)
{
    __shared__ int cur[1024];
    const int b    = blockIdx.x;
    const int tid  = threadIdx.x;
    const int dbase = b << 10;
    const int dmax  = min(1024, N_NODES - dbase);
    for (int j = tid; j < dmax; j += 256) cur[j] = rowptr[dbase + j];
    __syncthreads();
    const int s0 = rowptr[dbase];
    const int s1 = rowptr[dbase + dmax];
    for (int e = s0 + tid; e < s1; e += 256) {
        unsigned v = binned[e];
        int pos = atomicAdd(&cur[v & 1023u], 1);
        ssrc[pos] = (int)(v >> 10);
    }
}

// ---------------------------------------------------------------------------
// Gather layer 1: aggb[row,0:64] = bf16( sum_src x[src,:] ).
// 4 rows/wave; neighbors batched x8 (8 feature loads + 8 index prefetches in
// flight per iteration; masked slots clamp to `row` and multiply by 0).
// ---------------------------------------------------------------------------
__global__ __launch_bounds__(256) void gather1_kernel(
    const float* __restrict__ x, const int* __restrict__ rowptr,
    const int* __restrict__ ssrc, unsigned short* __restrict__ aggb)
{
    const int tid  = threadIdx.x;
    const int wv   = tid >> 6;
    const int lane = tid & 63;
    const int sub  = lane >> 4;
    const int li   = lane & 15;
    const int row  = blockIdx.x * 16 + wv * 4 + sub;

    const int b = rowptr[row], e = rowptr[row + 1];
    float4 acc = {0.f, 0.f, 0.f, 0.f};
    int s[8];
#pragma unroll
    for (int q = 0; q < 8; ++q) s[q] = (b + q < e) ? ssrc[b + q] : row;
    for (int j = b; j < e; j += 8) {
        int nn[8];
        const int jn = j + 8;
#pragma unroll
        for (int q = 0; q < 8; ++q) nn[q] = (jn + q < e) ? ssrc[jn + q] : row;
        float4 v[8];
#pragma unroll
        for (int q = 0; q < 8; ++q)
            v[q] = ((const float4*)(x + (size_t)s[q] * F_IN))[li];
#pragma unroll
        for (int q = 0; q < 8; ++q) {
            float w = (j + q < e) ? 1.f : 0.f;
            acc.x = fmaf(v[q].x, w, acc.x);
            acc.y = fmaf(v[q].y, w, acc.y);
            acc.z = fmaf(v[q].z, w, acc.z);
            acc.w = fmaf(v[q].w, w, acc.w);
        }
#pragma unroll
        for (int q = 0; q < 8; ++q) s[q] = nn[q];
    }
    us4 o;
    o.x = f2bf(acc.x); o.y = f2bf(acc.y); o.z = f2bf(acc.z); o.w = f2bf(acc.w);
    *(us4*)(aggb + (size_t)row * F_IN + li * 4) = o;
}

// ---------------------------------------------------------------------------
// Gather layer 2: aggb[row,0:128] = bf16( sum_src t1[src,:] ), batch x8.
// ---------------------------------------------------------------------------
__global__ __launch_bounds__(256) void gather2_kernel(
    const unsigned short* __restrict__ t1, const int* __restrict__ rowptr,
    const int* __restrict__ ssrc, unsigned short* __restrict__ aggb)
{
    const int tid  = threadIdx.x;
    const int wv   = tid >> 6;
    const int lane = tid & 63;
    const int sub  = lane >> 4;
    const int li   = lane & 15;
    const int row  = blockIdx.x * 16 + wv * 4 + sub;

    const int b = rowptr[row], e = rowptr[row + 1];
    float acc[8] = {};
    int s[8];
#pragma unroll
    for (int q = 0; q < 8; ++q) s[q] = (b + q < e) ? ssrc[b + q] : row;
    for (int j = b; j < e; j += 8) {
        int nn[8];
        const int jn = j + 8;
#pragma unroll
        for (int q = 0; q < 8; ++q) nn[q] = (jn + q < e) ? ssrc[jn + q] : row;
        bf16x8 v[8];
#pragma unroll
        for (int q = 0; q < 8; ++q)
            v[q] = *(const bf16x8*)(t1 + (size_t)s[q] * F_H + li * 8);
#pragma unroll
        for (int q = 0; q < 8; ++q) {
            float w = (j + q < e) ? 1.f : 0.f;
#pragma unroll
            for (int k = 0; k < 8; ++k)
                acc[k] = fmaf(bf2f((unsigned short)v[q][k]), w, acc[k]);
        }
#pragma unroll
        for (int q = 0; q < 8; ++q) s[q] = nn[q];
    }
    bf16x8 o;
#pragma unroll
    for (int k = 0; k < 8; ++k) o[k] = (short)f2bf(acc[k]);
    *(bf16x8*)(aggb + (size_t)row * F_H + li * 8) = o;
}

// ---------------------------------------------------------------------------
// MFMA GEMM: 32 rows/wave (2 subtiles), 128 rows/block, flat grid 1563.
// ALL A/X row-slices for the wave are loaded up front; weights staged ONCE
// per block into LDS (ds_read_b128, conflict-free in the K loop). Stats
// buffers overlaid on the weight LDS after the K loop.
// ---------------------------------------------------------------------------
template<int K, bool L2>
__global__ __launch_bounds__(256, 2) void gemm_mfma_kernel(
    const unsigned short* __restrict__ Ab,
    const float* __restrict__ Xf,
    const unsigned short* __restrict__ Xb,
    const bf16x8* __restrict__ Wlp, const bf16x8* __restrict__ Wrp,
    const float* __restrict__ bias,
    const float* __restrict__ c2, const float* __restrict__ degf,
    float* __restrict__ outF, unsigned short* __restrict__ outB,
    float* __restrict__ gsum, float* __restrict__ gsq)
{
    constexpr int KT = K / 32;
    constexpr int WHALF = 8 * KT * 64 * 8;        // shorts per weight array
    __shared__ short sW[2 * WHALF];               // Wl | Wr (stats overlaid later)

    const int tid  = threadIdx.x;
    const int lane = tid & 63;
    const int wv   = tid >> 6;
    const int m    = lane & 15;
    const int quad = lane >> 4;
    const int rowbase = blockIdx.x * 128 + wv * 32;

    int rc[2];
#pragma unroll
    for (int st = 0; st < 2; ++st) {
        int r = rowbase + st * 16 + m;
        rc[st] = r < N_NODES ? r : N_NODES - 1;
    }

    // ---- upfront load of the wave's full A and X row-slices (HBM/L3) ----
    bf16x8 aReg[2][KT], xReg[2][KT];
#pragma unroll
    for (int st = 0; st < 2; ++st) {
        const unsigned short* ap = Ab + (size_t)rc[st] * K + quad * 8;
#pragma unroll
        for (int kt = 0; kt < KT; ++kt)
            aReg[st][kt] = *(const bf16x8*)(ap + kt * 32);
    }
    if constexpr (L2) {
#pragma unroll
        for (int st = 0; st < 2; ++st) {
            const unsigned short* xp = Xb + (size_t)rc[st] * K + quad * 8;
#pragma unroll
            for (int kt = 0; kt < KT; ++kt)
                xReg[st][kt] = *(const bf16x8*)(xp + kt * 32);
        }
    } else {
        float4 xr[2][KT][2];
#pragma unroll
        for (int st = 0; st < 2; ++st) {
            const float* xp = Xf + (size_t)rc[st] * K + quad * 8;
#pragma unroll
            for (int kt = 0; kt < KT; ++kt) {
                xr[st][kt][0] = *(const float4*)(xp + kt * 32);
                xr[st][kt][1] = *(const float4*)(xp + kt * 32 + 4);
            }
        }
#pragma unroll
        for (int st = 0; st < 2; ++st)
#pragma unroll
            for (int kt = 0; kt < KT; ++kt) {
                xReg[st][kt][0] = (short)f2bf(xr[st][kt][0].x);
                xReg[st][kt][1] = (short)f2bf(xr[st][kt][0].y);
                xReg[st][kt][2] = (short)f2bf(xr[st][kt][0].z);
                xReg[st][kt][3] = (short)f2bf(xr[st][kt][0].w);
                xReg[st][kt][4] = (short)f2bf(xr[st][kt][1].x);
                xReg[st][kt][5] = (short)f2bf(xr[st][kt][1].y);
                xReg[st][kt][6] = (short)f2bf(xr[st][kt][1].z);
                xReg[st][kt][7] = (short)f2bf(xr[st][kt][1].w);
            }
    }

    // ---- stage packed weights into LDS (cooperative, once per block) ----
    {
        const short* wl = (const short*)Wlp;
        const short* wr = (const short*)Wrp;
#pragma unroll 4
        for (int i = 0; i < WHALF / (256 * 8); ++i) {
            int idx = (i * 256 + tid) * 8;
            *(bf16x8*)(sW + idx)         = *(const bf16x8*)(wl + idx);
            *(bf16x8*)(sW + WHALF + idx) = *(const bf16x8*)(wr + idx);
        }
    }

    // per-nt epilogue constants (col = nt*16 + m)
    float bcol[8], ccol[8];
#pragma unroll
    for (int nt = 0; nt < 8; ++nt) {
        bcol[nt] = bias[nt * 16 + m];
        if constexpr (L2) ccol[nt] = c2[nt * 16 + m];
    }

    f32x4 acc[2][8] = {};

    __syncthreads();   // weights staged (also drains this wave's A/X loads)

    // ---- K loop: LDS weight reads (ds_read_b128, conflict-free) + MFMA ----
    const short* wlL = sW + lane * 8;          // lane-consecutive 16B frags
    const short* wrL = sW + WHALF + lane * 8;
#pragma unroll
    for (int kt = 0; kt < KT; ++kt) {
#pragma unroll
        for (int nt = 0; nt < 8; ++nt) {
            bf16x8 wl = *(const bf16x8*)(wlL + (nt * KT + kt) * 512);
#pragma unroll
            for (int st = 0; st < 2; ++st)
                acc[st][nt] = __builtin_amdgcn_mfma_f32_16x16x32_bf16(
                    aReg[st][kt], wl, acc[st][nt], 0, 0, 0);
            bf16x8 wr = *(const bf16x8*)(wrL + (nt * KT + kt) * 512);
#pragma unroll
            for (int st = 0; st < 2; ++st)
                acc[st][nt] = __builtin_amdgcn_mfma_f32_16x16x32_bf16(
                    xReg[st][kt], wr, acc[st][nt], 0, 0, 0);
        }
    }

    // ---- epilogue: C/D layout col = lane&15, row = quad*4 + reg ----
    float stS[8] = {}, stQ[8] = {};
#pragma unroll
    for (int st = 0; st < 2; ++st) {
        const int orow = rowbase + st * 16 + quad * 4;
        float dg[4];
        if constexpr (L2) {
#pragma unroll
            for (int r = 0; r < 4; ++r) {
                int rr = orow + r;
                dg[r] = (rr < N_NODES) ? degf[rr] : 0.f;
            }
        }
#pragma unroll
        for (int nt = 0; nt < 8; ++nt) {
            int col = nt * 16 + m;
#pragma unroll
            for (int r = 0; r < 4; ++r) {
                int rr = orow + r;
                if (rr < N_NODES) {
                    float base = L2 ? fmaf(dg[r], ccol[nt], bcol[nt]) : bcol[nt];
                    float v = fmaxf(acc[st][nt][r] + base, 0.f);
                    if constexpr (L2) outF[(size_t)rr * 128 + col] = v;
                    else              outB[(size_t)rr * 128 + col] = f2bf(v);
                    stS[nt] += v;
                    stQ[nt] = fmaf(v, v, stQ[nt]);
                }
            }
        }
    }

    // ---- stats reduce: overlay sS/sQ on the (now dead) weight LDS ----
    float* sS = (float*)sW;
    float* sQ = ((float*)sW) + 128;
    __syncthreads();                      // all weight reads complete
    if (tid < 128) { sS[tid] = 0.f; sQ[tid] = 0.f; }
    __syncthreads();
#pragma unroll
    for (int nt = 0; nt < 8; ++nt) {
        atomicAdd(&sS[nt * 16 + m], stS[nt]);
        atomicAdd(&sQ[nt * 16 + m], stQ[nt]);
    }
    __syncthreads();
    const int rep = (blockIdx.x & 3) * 128;
    if (tid < 128) {
        atomicAdd(&gsum[rep + tid], sS[tid]);
        atomicAdd(&gsq[rep + tid],  sQ[tid]);
    }
}

// ---------------------------------------------------------------------------
// BN finalize: per-feature scale/shift (sums the 4 stats replicas).
// ---------------------------------------------------------------------------
__global__ void bn_finalize_kernel(
    const float* __restrict__ gsum, const float* __restrict__ gsq,
    const float* __restrict__ g, const float* __restrict__ be,
    float* __restrict__ scale, float* __restrict__ shift, float invN)
{
    int c = threadIdx.x;  // 128
    float s = gsum[c] + gsum[128 + c] + gsum[256 + c] + gsum[384 + c];
    float q = gsq[c]  + gsq[128 + c]  + gsq[256 + c]  + gsq[384 + c];
    float mean = s * invN;
    float var  = fmaxf(q * invN - mean * mean, 0.f);
    float sc   = g[c] * rsqrtf(var + BN_EPS);
    scale[c] = sc;
    shift[c] = be[c] - mean * sc;
}

// BN1 fold constants: c2 = shift1@W2l ; crb = shift1@W2r + b2
__global__ void bn_fold_kernel(
    const float* __restrict__ shift1, const float* __restrict__ W2l,
    const float* __restrict__ W2r, const float* __restrict__ b2,
    float* __restrict__ c2, float* __restrict__ crb)
{
    int col = threadIdx.x;  // 128
    float a = 0.f, r = 0.f;
    for (int k = 0; k < 128; ++k) {
        float s = shift1[k];
        a = fmaf(s, W2l[(size_t)k * 128 + col], a);
        r = fmaf(s, W2r[(size_t)k * 128 + col], r);
    }
    c2[col]  = a;
    crb[col] = r + b2[col];
}

// ---------------------------------------------------------------------------
// Final BN apply + ReLU (in place on d_out).
// ---------------------------------------------------------------------------
__global__ __launch_bounds__(256) void bn_apply_relu_kernel(
    float* __restrict__ h, const float* __restrict__ scale,
    const float* __restrict__ shift, int n4)
{
    int i = blockIdx.x * 256 + threadIdx.x;
    if (i >= n4) return;
    int cb = i & 31;
    float4 v  = ((float4*)h)[i];
    float4 sc = ((const float4*)scale)[cb];
    float4 sh = ((const float4*)shift)[cb];
    v.x = fmaxf(fmaf(v.x, sc.x, sh.x), 0.f);
    v.y = fmaxf(fmaf(v.y, sc.y, sh.y), 0.f);
    v.z = fmaxf(fmaf(v.z, sc.z, sh.z), 0.f);
    v.w = fmaxf(fmaf(v.w, sc.w, sh.w), 0.f);
    ((float4*)h)[i] = v;
}

extern "C" void kernel_launch(void* const* d_in, const int* in_sizes, int n_in,
                              void* d_out, int out_size, void* d_ws, size_t ws_size,
                              hipStream_t stream) {
    const float* x   = (const float*)d_in[0];
    const int*   ei  = (const int*)d_in[1];
    const float* W1l = (const float*)d_in[2];
    const float* b1  = (const float*)d_in[3];
    const float* W1r = (const float*)d_in[4];
    const float* g1  = (const float*)d_in[5];
    const float* be1 = (const float*)d_in[6];
    const float* W2l = (const float*)d_in[7];
    const float* b2  = (const float*)d_in[8];
    const float* W2r = (const float*)d_in[9];
    const float* g2  = (const float*)d_in[10];
    const float* be2 = (const float*)d_in[11];
    float* out = (float*)d_out;

    const int N = N_NODES, E = N_EDGES;
    const int NB1 = (N + 1023) / 1024;          // 196 scan blocks
    const int nT  = (N + 127) / 128;            // 1563 gemm blocks

    // Workspace layout (float units):
    float* ws     = (float*)d_ws;
    float* gsum1  = ws;          float* gsq1   = ws + 512;    // 4 replicas x 128
    float* gsum2  = ws + 1024;   float* gsq2   = ws + 1536;
    float* scale1 = ws + 2048;   float* shift1 = ws + 2176;
    float* scale2 = ws + 2304;   float* shift2 = ws + 2432;
    float* c2v    = ws + 2560;   float* crb    = ws + 2688;
    short* W1lp = (short*)(ws + 3072);                        // 4096 f
    short* W1rp = (short*)(ws + 3072 + 4096);                 // 4096 f
    short* W2lp = (short*)(ws + 3072 + 8192);                 // 8192 f
    short* W2rp = (short*)(ws + 3072 + 16384);                // 8192 f
    int*   deg    = (int*)(ws + 27648);                       // N
    int*   part   = deg + N;                                  // N
    int*   bsum   = part + N;                                 // 1024
    int*   rowptr = bsum + 1024;                              // N+1
    int*   bcursor= rowptr + (N + 1024);                      // 256 (old cursor slot)
    float* degf   = (float*)(bcursor + N);                    // N
    int*   ssrc   = (int*)(degf + N);                         // E
    unsigned short* t1   = (unsigned short*)(ssrc + E);       // N*128 bf16
    unsigned short* aggb = t1 + (size_t)N * F_H;              // N*128 bf16
    unsigned* binned = (unsigned*)aggb;                       // E u32 (dead until gather1)

    // ---- Graph build + layer-1 weight pack ----
    hipMemsetAsync(ws, 0, 2048 * sizeof(float), stream);      // stats replicas
    hipMemsetAsync(deg, 0, (size_t)N * sizeof(int), stream);
    pack_weights_kernel<<<4, 256, 0, stream>>>(W1l, nullptr, W1lp, 2);
    pack_weights_kernel<<<4, 256, 0, stream>>>(W1r, nullptr, W1rp, 2);
    hist_kernel<<<(E + 255) / 256, 256, 0, stream>>>(ei, deg, E);
    scan1_kernel<<<NB1, 256, 0, stream>>>(deg, part, bsum, N);
    scan2_kernel<<<1, 256, 0, stream>>>(bsum, NB1);
    scan3_kernel<<<(N + 255) / 256, 256, 0, stream>>>(part, bsum, deg, rowptr,
                                                      bcursor, degf, N, E);
    bin_kernel<<<BINB, 256, 0, stream>>>(ei, bcursor, binned, E);
    scatter_kernel<<<NBUK, 256, 0, stream>>>(binned, rowptr, ssrc);

    // ---- Layer 1 ----
    gather1_kernel<<<N / 16, 256, 0, stream>>>(x, rowptr, ssrc, aggb);
    gemm_mfma_kernel<F_IN, false><<<nT, 256, 0, stream>>>(
        aggb, x, nullptr, (const bf16x8*)W1lp, (const bf16x8*)W1rp, b1,
        nullptr, nullptr, nullptr, t1, gsum1, gsq1);
    bn_finalize_kernel<<<1, 128, 0, stream>>>(gsum1, gsq1, g1, be1,
                                              scale1, shift1, 1.f / N);

    // ---- Layer 2 (BN1 folded: scale1 into weights, shift1 into c2/crb) ----
    pack_weights_kernel<<<8, 256, 0, stream>>>(W2l, scale1, W2lp, 4);
    pack_weights_kernel<<<8, 256, 0, stream>>>(W2r, scale1, W2rp, 4);
    bn_fold_kernel<<<1, 128, 0, stream>>>(shift1, W2l, W2r, b2, c2v, crb);
    gather2_kernel<<<N / 16, 256, 0, stream>>>(t1, rowptr, ssrc, aggb);
    gemm_mfma_kernel<F_H, true><<<nT, 256, 0, stream>>>(
        aggb, nullptr, t1, (const bf16x8*)W2lp, (const bf16x8*)W2rp, crb,
        c2v, degf, out, nullptr, gsum2, gsq2);
    bn_finalize_kernel<<<1, 128, 0, stream>>>(gsum2, gsq2, g2, be2,
                                              scale2, shift2, 1.f / N);
    bn_apply_relu_kernel<<<(N * F_H / 4 + 255) / 256, 256, 0, stream>>>(
        out, scale2, shift2, N * F_H / 4);
}